// Round 15
// baseline (261.045 us; speedup 1.0000x reference)
//
#include <hip/hip_runtime.h>
#include <hip/hip_bf16.h>
#include <math.h>

#define NCLS 40
#define H2S 64         // h2b row stride (ushorts): 40 bf16 + el2/er2 fp32 in pad
#define PWG 256        // partition workgroups
#define BSH 9          // log2(nodes per bucket) = 512 nodes/bucket  (NB <= 256!)
#define NBMAX 512
#define SRCB 23        // src packed in low 23 bits, local node id in high 9
#define CSRCAP 14336   // staged edges per bucket (56 KB LDS)

typedef __attribute__((ext_vector_type(8))) short bf16x8;
typedef __attribute__((ext_vector_type(4))) float f32x4;

__device__ inline float bf2f(ushort u) {
    unsigned v = ((unsigned)u) << 16;
    float f;
    __builtin_memcpy(&f, &v, 4);
    return f;
}
__device__ inline ushort f2bf(float f) {
    unsigned v;
    __builtin_memcpy(&v, &f, 4);
    unsigned r = (v + 0x7FFFu + ((v >> 16) & 1u)) >> 16;
    return (ushort)r;
}
// pack two floats -> two bf16 (round-half-up) in one word: [bf(b)<<16 | bf(a)]
__device__ inline unsigned pkbf(float a, float b) {
    unsigned ua, ub;
    __builtin_memcpy(&ua, &a, 4);
    __builtin_memcpy(&ub, &b, 4);
    return __builtin_amdgcn_perm(ub + 0x8000u, ua + 0x8000u, 0x07060302u);
}

// ---------------------------------------------------------------------------
// hist_prep: blocks [0,PWG) per-WG bucket histogram -> hist[b*PWG + wg];
//            blocks [PWG,PWG+128) transpose W1 -> bf16 W1t[64][512];
//            block PWG+128 computes wal2/war2.
// ---------------------------------------------------------------------------
__global__ __launch_bounds__(256) void hist_prep_kernel(
    const int* __restrict__ dst, int* __restrict__ hist, int Ee, int chunk, int NB,
    const float* __restrict__ W1, ushort* __restrict__ W1t,
    const float* __restrict__ W2, const float* __restrict__ al2,
    const float* __restrict__ ar2, float* __restrict__ wal2,
    float* __restrict__ war2)
{
    if (blockIdx.x >= PWG) {
        int bb = blockIdx.x - PWG;
        if (bb < 128) {
            int id = bb * 256 + threadIdx.x;  // 32768
            int k = id >> 6, c = id & 63;
            W1t[c * 512 + k] = f2bf(W1[k * 64 + c]);
        } else if (threadIdx.x < 64) {
            int k = threadIdx.x;
            float a = 0.f, b = 0.f;
            for (int c = 0; c < NCLS; c++) {
                float w = W2[k * NCLS + c];
                a += w * al2[c];
                b += w * ar2[c];
            }
            wal2[k] = a;
            war2[k] = b;
        }
        return;
    }
    __shared__ int lh[256];
    const int wg = blockIdx.x, tid = threadIdx.x;
    lh[tid] = 0;
    __syncthreads();
    const int beg = wg * chunk;
    const int endv = min(Ee, beg + chunk);
#pragma unroll 4
    for (int i = beg + tid; i < endv; i += 256) atomicAdd(&lh[dst[i] >> BSH], 1);
    __syncthreads();
    if (tid < NB) hist[tid * PWG + wg] = lh[tid];
}

// ---------------------------------------------------------------------------
// scanA: per-bucket exclusive scan of its PWG-length row; bucket total out.
// ---------------------------------------------------------------------------
__global__ __launch_bounds__(256) void scanA_kernel(int* __restrict__ hist,
                                                    int* __restrict__ bucketTot)
{
    __shared__ int s[256];
    const int b = blockIdx.x, tid = threadIdx.x;
    int v = hist[b * PWG + tid];
    s[tid] = v;
    __syncthreads();
#pragma unroll
    for (int o = 1; o < 256; o <<= 1) {
        int t = (tid >= o) ? s[tid - o] : 0;
        __syncthreads();
        s[tid] += t;
        __syncthreads();
    }
    hist[b * PWG + tid] = s[tid] - v;  // exclusive within bucket
    if (tid == 255) bucketTot[b] = s[255];
}

// ---------------------------------------------------------------------------
// part_gemm1: role-split fused kernel.
//  blocks [0,PWG): partition — computes bucketBase scan in LDS from bucketTot,
//    then scatters edges (packed 4B) into private per-bucket sub-regions.
//  blocks [PWG,..): GEMM1 — barrier-free, LDS-free. Each wave owns 16 rows;
//    A fragments loaded directly from x (fp32->bf16 via v_perm), B fragments
//    direct from W1t (L1/L2-resident). 8 MFMA per K-step, zero sync.
//    Fused el1/er1 epilogue.
// ---------------------------------------------------------------------------
__global__ __launch_bounds__(256) void part_gemm1_kernel(
    const int* __restrict__ src, const int* __restrict__ dst,
    const int* __restrict__ hist, const int* __restrict__ bucketTot,
    unsigned* __restrict__ ebuf, int Ee, int chunk, int NB,
    const float* __restrict__ x, const ushort* __restrict__ W1t,
    const float* __restrict__ al1, const float* __restrict__ ar1,
    ushort* __restrict__ h1b, float* __restrict__ el1,
    float* __restrict__ er1, int Nn)
{
    __shared__ int cur[NBMAX];   // 2 KB (partition role only)
    __shared__ int stmp[256];    // 1 KB

    if (blockIdx.x < PWG) {
        // ---------------- partition role -----------------------------------
        const int wg = blockIdx.x, tid = threadIdx.x;
        int v = (tid < NB) ? bucketTot[tid] : 0;
        stmp[tid] = v;
        __syncthreads();
#pragma unroll
        for (int o = 1; o < 256; o <<= 1) {
            int t = (tid >= o) ? stmp[tid - o] : 0;
            __syncthreads();
            stmp[tid] += t;
            __syncthreads();
        }
        if (tid < NB) cur[tid] = hist[tid * PWG + wg] + (stmp[tid] - v);
        __syncthreads();
        const int beg = wg * chunk;
        const int endv = min(Ee, beg + chunk);
        for (int i = beg + tid; i < endv; i += 256) {
            int d = dst[i];
            int p = atomicAdd(&cur[d >> BSH], 1);
            ebuf[p] = ((unsigned)(d & ((1 << BSH) - 1)) << SRCB) | (unsigned)src[i];
        }
        return;
    }

    // ---------------- GEMM1 role (barrier-free, LDS-free) ------------------
    const int t = threadIdx.x;
    const int lane = t & 63, w = t >> 6;
    const int tile = (blockIdx.x - PWG) * 64;
    const int r = lane & 15, g = lane >> 4;

    const int row = tile + w * 16 + r;
    const int rowc = min(row, Nn - 1);
    const float* xrow = x + (size_t)rowc * 512 + g * 8;
    const ushort* wbase = W1t + g * 8;

    f32x4 acc[4] = {};

#pragma unroll 2
    for (int k0 = 0; k0 < 512; k0 += 64) {
        // A: 16 fp32 (k0+g*8..+7 and k0+32+g*8..+7)
        float4 fA0 = *(const float4*)(xrow + k0);
        float4 fA1 = *(const float4*)(xrow + k0 + 4);
        float4 fA2 = *(const float4*)(xrow + k0 + 32);
        float4 fA3 = *(const float4*)(xrow + k0 + 36);
        // B: 8 bf16x8 fragments (L1/L2-resident)
        bf16x8 bf0[4], bf1[4];
#pragma unroll
        for (int cb = 0; cb < 4; cb++) {
            bf0[cb] = *(const bf16x8*)(wbase + (cb * 16 + r) * 512 + k0);
            bf1[cb] = *(const bf16x8*)(wbase + (cb * 16 + r) * 512 + k0 + 32);
        }
        uint4 a0w, a1w;
        a0w.x = pkbf(fA0.x, fA0.y); a0w.y = pkbf(fA0.z, fA0.w);
        a0w.z = pkbf(fA1.x, fA1.y); a0w.w = pkbf(fA1.z, fA1.w);
        a1w.x = pkbf(fA2.x, fA2.y); a1w.y = pkbf(fA2.z, fA2.w);
        a1w.z = pkbf(fA3.x, fA3.y); a1w.w = pkbf(fA3.z, fA3.w);
        bf16x8 af0, af1;
        __builtin_memcpy(&af0, &a0w, 16);
        __builtin_memcpy(&af1, &a1w, 16);
#pragma unroll
        for (int cb = 0; cb < 4; cb++)
            acc[cb] = __builtin_amdgcn_mfma_f32_16x16x32_bf16(af0, bf0[cb], acc[cb], 0, 0, 0);
#pragma unroll
        for (int cb = 0; cb < 4; cb++)
            acc[cb] = __builtin_amdgcn_mfma_f32_16x16x32_bf16(af1, bf1[cb], acc[cb], 0, 0, 0);
    }

    // epilogue: store h1b + fused el1/er1 from fp32 acc.
    float alv[4], arv[4];
#pragma unroll
    for (int cb = 0; cb < 4; cb++) {
        alv[cb] = al1[cb * 16 + r];
        arv[cb] = ar1[cb * 16 + r];
    }
#pragma unroll
    for (int v = 0; v < 4; v++) {
        int orow = tile + w * 16 + g * 4 + v;
        bool ok = orow < Nn;
#pragma unroll
        for (int cb = 0; cb < 4; cb++) {
            if (ok) h1b[(size_t)orow * 64 + cb * 16 + r] = f2bf(acc[cb][v]);
            float pel = acc[cb][v] * alv[cb];
            float per = acc[cb][v] * arv[cb];
            pel += __shfl_xor(pel, 1); per += __shfl_xor(per, 1);
            pel += __shfl_xor(pel, 2); per += __shfl_xor(per, 2);
            pel += __shfl_xor(pel, 4); per += __shfl_xor(per, 4);
            if (ok && (r & 7) == 0) {
                int head = cb * 2 + (r >> 3);
                el1[orow * 8 + head] = pel;
                er1[orow * 8 + head] = per;
            }
        }
    }
}

// ---------------------------------------------------------------------------
// bucket_csr: derives its own [bb,be) from bucketTot scan; LDS-staged edges ->
// node histogram -> scan -> row_start + perm_src scatter in bucket window.
// ---------------------------------------------------------------------------
__global__ __launch_bounds__(512) void bucket_csr_kernel(const unsigned* __restrict__ ebuf,
                                                         const int* __restrict__ bucketTot,
                                                         int* __restrict__ row_start,
                                                         int* __restrict__ perm_src,
                                                         int Nn, int Ee, int NB)
{
    __shared__ unsigned stage[CSRCAP];
    __shared__ int cnt[512];
    __shared__ int s[512];
    __shared__ int cur[512];
    __shared__ int bt[256];
    const int b = blockIdx.x, tid = threadIdx.x;
    const int base = b << BSH;

    // inclusive scan of bucketTot (NB <= 256) to derive bb/be
    if (tid < 256) bt[tid] = (tid < NB) ? bucketTot[tid] : 0;
    __syncthreads();
#pragma unroll
    for (int o = 1; o < 256; o <<= 1) {
        int t = (tid >= o && tid < 256) ? bt[tid - o] : 0;
        __syncthreads();
        if (tid < 256) bt[tid] += t;
        __syncthreads();
    }
    const int be = bt[b];
    const int bb = be - bucketTot[b];
    const int m = be - bb;

    cnt[tid] = 0;
    __syncthreads();
    for (int idx = tid; idx < m; idx += 512) {
        unsigned pk = ebuf[bb + idx];
        if (idx < CSRCAP) stage[idx] = pk;
        atomicAdd(&cnt[pk >> SRCB], 1);
    }
    __syncthreads();
    int v = cnt[tid];
    s[tid] = v;
    __syncthreads();
#pragma unroll
    for (int o = 1; o < 512; o <<= 1) {
        int t = (tid >= o) ? s[tid - o] : 0;
        __syncthreads();
        s[tid] += t;
        __syncthreads();
    }
    const int off = bb + s[tid] - v;
    const int node = base + tid;
    if (node < Nn) row_start[node] = off;
    cur[tid] = off;
    __syncthreads();
    for (int idx = tid; idx < m; idx += 512) {
        unsigned pk = (idx < CSRCAP) ? stage[idx] : ebuf[bb + idx];
        int p = atomicAdd(&cur[pk >> SRCB], 1);
        perm_src[p] = (int)(pk & ((1u << SRCB) - 1u));
    }
    if (b == NB - 1 && tid == 0) row_start[Nn] = Ee;
}

// ---------------------------------------------------------------------------
// agg1: one wave per dst node, 16 edges in flight per iteration.
// Lane group g = lane>>4 serves edges j+g, j+4+g, j+8+g, j+12+g; lane
// q = lane&15 loads features 4q..4q+3 as ushort4 (8B). Head h = q>>1.
// ---------------------------------------------------------------------------
__global__ __launch_bounds__(256) void agg1_kernel(
    const ushort* __restrict__ h1b, const float* __restrict__ el1,
    const float* __restrict__ er1, const int* __restrict__ row_start,
    const int* __restrict__ perm_src, const float* __restrict__ b1,
    ushort* __restrict__ hmidb, int Nn)
{
    const int wid = (blockIdx.x * blockDim.x + threadIdx.x) >> 6;
    const int lane = threadIdx.x & 63;
    if (wid >= Nn) return;
    const int g = lane >> 4;      // edge sub-group 0..3
    const int q = lane & 15;      // feature quad
    const int h = q >> 1;         // head
    const int beg = row_start[wid], end = row_start[wid + 1];
    const float er = er1[wid * 8 + h];

    float a0 = 0.f, a1 = 0.f, a2 = 0.f, a3 = 0.f, denom = 0.f;
    for (int i0 = beg; i0 < end; i0 += 64) {
        const int cnt = min(end - i0, 64);
        int pv = (i0 + lane < end) ? perm_src[i0 + lane] : 0;
        for (int j = 0; j < cnt; j += 16) {
            const int e0 = j + g, e1 = j + 4 + g, e2 = j + 8 + g, e3 = j + 12 + g;
            const int s0 = __shfl(pv, min(e0, cnt - 1));
            const int s1 = __shfl(pv, min(e1, cnt - 1));
            const int s2 = __shfl(pv, min(e2, cnt - 1));
            const int s3 = __shfl(pv, min(e3, cnt - 1));
            ushort4 r0 = *(const ushort4*)&h1b[(size_t)s0 * 64 + q * 4];
            ushort4 r1 = *(const ushort4*)&h1b[(size_t)s1 * 64 + q * 4];
            ushort4 r2 = *(const ushort4*)&h1b[(size_t)s2 * 64 + q * 4];
            ushort4 r3 = *(const ushort4*)&h1b[(size_t)s3 * 64 + q * 4];
            float x0 = el1[s0 * 8 + h];
            float x1 = el1[s1 * 8 + h];
            float x2 = el1[s2 * 8 + h];
            float x3 = el1[s3 * 8 + h];
            float e;
            e = x0 + er; e = (e >= 0.f) ? e : 0.2f * e;
            float w0 = (e0 < cnt) ? __expf(e) : 0.f;
            e = x1 + er; e = (e >= 0.f) ? e : 0.2f * e;
            float w1 = (e1 < cnt) ? __expf(e) : 0.f;
            e = x2 + er; e = (e >= 0.f) ? e : 0.2f * e;
            float w2 = (e2 < cnt) ? __expf(e) : 0.f;
            e = x3 + er; e = (e >= 0.f) ? e : 0.2f * e;
            float w3 = (e3 < cnt) ? __expf(e) : 0.f;
            denom += (w0 + w1) + (w2 + w3);
            a0 += bf2f(r0.x) * w0 + bf2f(r1.x) * w1 + bf2f(r2.x) * w2 + bf2f(r3.x) * w3;
            a1 += bf2f(r0.y) * w0 + bf2f(r1.y) * w1 + bf2f(r2.y) * w2 + bf2f(r3.y) * w3;
            a2 += bf2f(r0.z) * w0 + bf2f(r1.z) * w1 + bf2f(r2.z) * w2 + bf2f(r3.z) * w3;
            a3 += bf2f(r0.w) * w0 + bf2f(r1.w) * w1 + bf2f(r2.w) * w2 + bf2f(r3.w) * w3;
        }
    }
    // merge the 4 edge groups
    denom += __shfl_xor(denom, 16); denom += __shfl_xor(denom, 32);
    a0 += __shfl_xor(a0, 16); a0 += __shfl_xor(a0, 32);
    a1 += __shfl_xor(a1, 16); a1 += __shfl_xor(a1, 32);
    a2 += __shfl_xor(a2, 16); a2 += __shfl_xor(a2, 32);
    a3 += __shfl_xor(a3, 16); a3 += __shfl_xor(a3, 32);
    if (g == 0) {
        const float4 bv = *(const float4*)&b1[q * 4];
        const float inv = 1.f / (denom + 1e-9f);
        float v0 = a0 * inv + bv.x;
        float v1 = a1 * inv + bv.y;
        float v2 = a2 * inv + bv.z;
        float v3 = a3 * inv + bv.w;
        v0 = (v0 > 0.f) ? v0 : expm1f(v0);
        v1 = (v1 > 0.f) ? v1 : expm1f(v1);
        v2 = (v2 > 0.f) ? v2 : expm1f(v2);
        v3 = (v3 > 0.f) ? v3 : expm1f(v3);
        uint2 o;
        o.x = pkbf(v0, v1);
        o.y = pkbf(v2, v3);
        *(uint2*)&hmidb[(size_t)wid * 64 + q * 4] = o;
    }
}

// ---------------------------------------------------------------------------
// GEMM2: h2b = hmid @ W2 (bf16 in, bf16 out, padded rows w/ embedded el2/er2).
// One thread per node (lane-parallel over nodes; W2 broadcast from LDS).
// ---------------------------------------------------------------------------
__global__ __launch_bounds__(256) void gemm2_kernel(
    const ushort* __restrict__ hmidb, const float* __restrict__ W2,
    const float* __restrict__ wal2, const float* __restrict__ war2,
    ushort* __restrict__ h2b, int Nn)
{
    __shared__ float w2s[64 * NCLS];
    __shared__ float wals[64], wars[64];
    for (int i = threadIdx.x; i < 64 * NCLS; i += blockDim.x) w2s[i] = W2[i];
    if (threadIdx.x < 64) {
        wals[threadIdx.x] = wal2[threadIdx.x];
        wars[threadIdx.x] = war2[threadIdx.x];
    }
    __syncthreads();
    int n = blockIdx.x * blockDim.x + threadIdx.x;
    if (n >= Nn) return;

    float out[NCLS];
#pragma unroll
    for (int c = 0; c < NCLS; c++) out[c] = 0.f;
    float accel = 0.f, accer = 0.f;

#pragma unroll 4
    for (int k4 = 0; k4 < 16; k4++) {
        ushort4 u = *(const ushort4*)&hmidb[(size_t)n * 64 + k4 * 4];
        float h0 = bf2f(u.x), h1 = bf2f(u.y), h2 = bf2f(u.z), h3 = bf2f(u.w);
        accel += h0 * wals[k4 * 4] + h1 * wals[k4 * 4 + 1] + h2 * wals[k4 * 4 + 2] + h3 * wals[k4 * 4 + 3];
        accer += h0 * wars[k4 * 4] + h1 * wars[k4 * 4 + 1] + h2 * wars[k4 * 4 + 2] + h3 * wars[k4 * 4 + 3];
#pragma unroll
        for (int c = 0; c < NCLS; c++) {
            out[c] += h0 * w2s[(k4 * 4 + 0) * NCLS + c] + h1 * w2s[(k4 * 4 + 1) * NCLS + c] +
                      h2 * w2s[(k4 * 4 + 2) * NCLS + c] + h3 * w2s[(k4 * 4 + 3) * NCLS + c];
        }
    }
    ushort* row = h2b + (size_t)n * H2S;
#pragma unroll
    for (int c = 0; c < NCLS; c += 2) {
        *(unsigned*)&row[c] = pkbf(out[c], out[c + 1]);
    }
    ((float*)row)[20] = accel;  // el2
    ((float*)row)[21] = accer;  // er2
}

// ---------------------------------------------------------------------------
// agg2 + log_softmax: one wave per dst node, 16 edges in flight/iteration.
// Group g serves edges j+g, j+4+g, j+8+g, j+12+g; lanes q<10 load the 80B
// class row as ushort4; el2 read from the same 128B line (embedded).
// ---------------------------------------------------------------------------
__global__ __launch_bounds__(256) void agg2_kernel(
    const ushort* __restrict__ h2b, const int* __restrict__ row_start,
    const int* __restrict__ perm_src, const float* __restrict__ b2,
    float* __restrict__ out, int Nn)
{
    const int wid = (blockIdx.x * blockDim.x + threadIdx.x) >> 6;
    const int lane = threadIdx.x & 63;
    if (wid >= Nn) return;
    const int g = lane >> 4;
    const int q = lane & 15;
    const int beg = row_start[wid], end = row_start[wid + 1];
    const float er = ((const float*)(h2b + (size_t)wid * H2S))[21];

    float a0 = 0.f, a1 = 0.f, a2 = 0.f, a3 = 0.f, denom = 0.f;
    for (int i0 = beg; i0 < end; i0 += 64) {
        const int cnt = min(end - i0, 64);
        int pv = (i0 + lane < end) ? perm_src[i0 + lane] : 0;
        for (int j = 0; j < cnt; j += 16) {
            const int e0 = j + g, e1 = j + 4 + g, e2 = j + 8 + g, e3 = j + 12 + g;
            const int s0 = __shfl(pv, min(e0, cnt - 1));
            const int s1 = __shfl(pv, min(e1, cnt - 1));
            const int s2 = __shfl(pv, min(e2, cnt - 1));
            const int s3 = __shfl(pv, min(e3, cnt - 1));
            const ushort* rp0 = h2b + (size_t)s0 * H2S;
            const ushort* rp1 = h2b + (size_t)s1 * H2S;
            const ushort* rp2 = h2b + (size_t)s2 * H2S;
            const ushort* rp3 = h2b + (size_t)s3 * H2S;
            ushort4 r0 = *(const ushort4*)(rp0 + q * 4);
            ushort4 r1 = *(const ushort4*)(rp1 + q * 4);
            ushort4 r2 = *(const ushort4*)(rp2 + q * 4);
            ushort4 r3 = *(const ushort4*)(rp3 + q * 4);
            float x0 = ((const float*)rp0)[20];
            float x1 = ((const float*)rp1)[20];
            float x2 = ((const float*)rp2)[20];
            float x3 = ((const float*)rp3)[20];
            float e;
            e = x0 + er; e = (e >= 0.f) ? e : 0.2f * e;
            float w0 = (e0 < cnt) ? __expf(e) : 0.f;
            e = x1 + er; e = (e >= 0.f) ? e : 0.2f * e;
            float w1 = (e1 < cnt) ? __expf(e) : 0.f;
            e = x2 + er; e = (e >= 0.f) ? e : 0.2f * e;
            float w2 = (e2 < cnt) ? __expf(e) : 0.f;
            e = x3 + er; e = (e >= 0.f) ? e : 0.2f * e;
            float w3 = (e3 < cnt) ? __expf(e) : 0.f;
            denom += (w0 + w1) + (w2 + w3);
            a0 += bf2f(r0.x) * w0 + bf2f(r1.x) * w1 + bf2f(r2.x) * w2 + bf2f(r3.x) * w3;
            a1 += bf2f(r0.y) * w0 + bf2f(r1.y) * w1 + bf2f(r2.y) * w2 + bf2f(r3.y) * w3;
            a2 += bf2f(r0.z) * w0 + bf2f(r1.z) * w1 + bf2f(r2.z) * w2 + bf2f(r3.z) * w3;
            a3 += bf2f(r0.w) * w0 + bf2f(r1.w) * w1 + bf2f(r2.w) * w2 + bf2f(r3.w) * w3;
        }
    }
    // merge the 4 edge groups
    denom += __shfl_xor(denom, 16); denom += __shfl_xor(denom, 32);
    a0 += __shfl_xor(a0, 16); a0 += __shfl_xor(a0, 32);
    a1 += __shfl_xor(a1, 16); a1 += __shfl_xor(a1, 32);
    a2 += __shfl_xor(a2, 16); a2 += __shfl_xor(a2, 32);
    a3 += __shfl_xor(a3, 16); a3 += __shfl_xor(a3, 32);

    const bool act = (g == 0) && (q < 10);
    float v0, v1, v2, v3;
    if (act) {
        const float4 bv = *(const float4*)&b2[q * 4];
        const float inv = 1.f / (denom + 1e-9f);
        v0 = a0 * inv + bv.x;
        v1 = a1 * inv + bv.y;
        v2 = a2 * inv + bv.z;
        v3 = a3 * inv + bv.w;
    } else {
        v0 = v1 = v2 = v3 = -1e30f;
    }
    // log_softmax over 40 classes (10 lanes x 4)
    float mx = fmaxf(fmaxf(v0, v1), fmaxf(v2, v3));
#pragma unroll
    for (int o = 1; o < 64; o <<= 1) mx = fmaxf(mx, __shfl_xor(mx, o));
    float sx = act ? (__expf(v0 - mx) + __expf(v1 - mx) + __expf(v2 - mx) + __expf(v3 - mx)) : 0.f;
#pragma unroll
    for (int o = 1; o < 64; o <<= 1) sx += __shfl_xor(sx, o);
    if (act) {
        float lg = mx + __logf(sx);
        float4 o4 = make_float4(v0 - lg, v1 - lg, v2 - lg, v3 - lg);
        *(float4*)&out[(size_t)wid * NCLS + q * 4] = o4;
    }
}

// ---------------------------------------------------------------------------
extern "C" void kernel_launch(void* const* d_in, const int* in_sizes, int n_in,
                              void* d_out, int out_size, void* d_ws, size_t ws_size,
                              hipStream_t stream)
{
    const float* x   = (const float*)d_in[0];
    const int*   src = (const int*)d_in[1];
    const int*   dst = (const int*)d_in[2];
    const float* W1  = (const float*)d_in[3];
    const float* al1 = (const float*)d_in[4];
    const float* ar1 = (const float*)d_in[5];
    const float* b1  = (const float*)d_in[6];
    const float* W2  = (const float*)d_in[7];
    const float* al2 = (const float*)d_in[8];
    const float* ar2 = (const float*)d_in[9];
    const float* b2  = (const float*)d_in[10];
    float* out = (float*)d_out;

    const int Nn = in_sizes[0] / 512;
    const int Ee = in_sizes[1];
    const int NB = (Nn + (1 << BSH) - 1) >> BSH;   // buckets of 512 nodes (<=256)
    const int chunk = (Ee + PWG - 1) / PWG;

    // workspace layout (16B-aligned bump allocator)
    char* wsb = (char*)d_ws;
    size_t off = 0;
    auto alloc = [&](size_t bytes) -> void* {
        off = (off + 15) & ~(size_t)15;
        void* p = wsb + off;
        off += bytes;
        return p;
    };
    ushort* h1b   = (ushort*)alloc((size_t)Nn * 64 * 2);
    ushort* hmidb = (ushort*)alloc((size_t)Nn * 64 * 2);
    ushort* h2b   = (ushort*)alloc((size_t)Nn * H2S * 2);
    ushort* W1t   = (ushort*)alloc(64 * 512 * 2);
    float* el1  = (float*)alloc((size_t)Nn * 8 * 4);
    float* er1  = (float*)alloc((size_t)Nn * 8 * 4);
    float* wal2 = (float*)alloc(64 * 4);
    float* war2 = (float*)alloc(64 * 4);
    int* row_start  = (int*)alloc((size_t)(Nn + 1) * 4);
    int* hist       = (int*)alloc((size_t)NB * PWG * 4);
    int* bucketTot  = (int*)alloc((size_t)NB * 4);
    int* perm_src   = (int*)alloc((size_t)Ee * 4);
    unsigned* ebuf  = (unsigned*)alloc((size_t)Ee * 4);

    // CSR build + weight prep; partition overlapped with gemm1 (role-split)
    hist_prep_kernel<<<PWG + 129, 256, 0, stream>>>(dst, hist, Ee, chunk, NB,
                                                    W1, W1t, W2, al2, ar2, wal2, war2);
    scanA_kernel<<<NB, 256, 0, stream>>>(hist, bucketTot);
    part_gemm1_kernel<<<PWG + (Nn + 63) / 64, 256, 0, stream>>>(
        src, dst, hist, bucketTot, ebuf, Ee, chunk, NB,
        x, W1t, al1, ar1, h1b, el1, er1, Nn);
    bucket_csr_kernel<<<NB, 512, 0, stream>>>(ebuf, bucketTot, row_start, perm_src, Nn, Ee, NB);

    // layer 1 aggregation
    agg1_kernel<<<(Nn + 3) / 4, 256, 0, stream>>>(h1b, el1, er1, row_start, perm_src, b1, hmidb, Nn);

    // layer 2
    gemm2_kernel<<<(Nn + 255) / 256, 256, 0, stream>>>(hmidb, W2, wal2, war2, h2b, Nn);
    agg2_kernel<<<(Nn + 3) / 4, 256, 0, stream>>>(h2b, row_start, perm_src, b2, out, Nn);
}

// Round 16
// 223.283 us; speedup vs baseline: 1.1691x; 1.1691x over previous
//
#include <hip/hip_runtime.h>
#include <hip/hip_bf16.h>
#include <math.h>

#define NCLS 40
#define H2S 64         // h2b row stride (ushorts): 40 bf16 + el2/er2 fp32 in pad
#define PWG 256        // partition workgroups
#define BSH 9          // log2(nodes per bucket) = 512 nodes/bucket  (NB <= 256!)
#define NBMAX 512
#define SRCB 23        // src packed in low 23 bits, local node id in high 9
#define CSRCAP 14336   // staged edges per bucket (56 KB LDS)

typedef __attribute__((ext_vector_type(8))) short bf16x8;
typedef __attribute__((ext_vector_type(4))) float f32x4;

__device__ inline float bf2f(ushort u) {
    unsigned v = ((unsigned)u) << 16;
    float f;
    __builtin_memcpy(&f, &v, 4);
    return f;
}
__device__ inline ushort f2bf(float f) {
    unsigned v;
    __builtin_memcpy(&v, &f, 4);
    unsigned r = (v + 0x7FFFu + ((v >> 16) & 1u)) >> 16;
    return (ushort)r;
}
// pack two floats -> two bf16 (round-half-up) in one word: [bf(b)<<16 | bf(a)]
__device__ inline unsigned pkbf(float a, float b) {
    unsigned ua, ub;
    __builtin_memcpy(&ua, &a, 4);
    __builtin_memcpy(&ub, &b, 4);
    return __builtin_amdgcn_perm(ub + 0x8000u, ua + 0x8000u, 0x07060302u);
}

// ---------------------------------------------------------------------------
// hist_prep: blocks [0,PWG) per-WG bucket histogram -> hist[b*PWG + wg];
//            blocks [PWG,PWG+128) transpose W1 -> bf16 W1t[64][512];
//            block PWG+128 computes wal2/war2.
// ---------------------------------------------------------------------------
__global__ __launch_bounds__(256) void hist_prep_kernel(
    const int* __restrict__ dst, int* __restrict__ hist, int Ee, int chunk, int NB,
    const float* __restrict__ W1, ushort* __restrict__ W1t,
    const float* __restrict__ W2, const float* __restrict__ al2,
    const float* __restrict__ ar2, float* __restrict__ wal2,
    float* __restrict__ war2)
{
    if (blockIdx.x >= PWG) {
        int bb = blockIdx.x - PWG;
        if (bb < 128) {
            int id = bb * 256 + threadIdx.x;  // 32768
            int k = id >> 6, c = id & 63;
            W1t[c * 512 + k] = f2bf(W1[k * 64 + c]);
        } else if (threadIdx.x < 64) {
            int k = threadIdx.x;
            float a = 0.f, b = 0.f;
            for (int c = 0; c < NCLS; c++) {
                float w = W2[k * NCLS + c];
                a += w * al2[c];
                b += w * ar2[c];
            }
            wal2[k] = a;
            war2[k] = b;
        }
        return;
    }
    __shared__ int lh[256];
    const int wg = blockIdx.x, tid = threadIdx.x;
    lh[tid] = 0;
    __syncthreads();
    const int beg = wg * chunk;
    const int endv = min(Ee, beg + chunk);
#pragma unroll 4
    for (int i = beg + tid; i < endv; i += 256) atomicAdd(&lh[dst[i] >> BSH], 1);
    __syncthreads();
    if (tid < NB) hist[tid * PWG + wg] = lh[tid];
}

// ---------------------------------------------------------------------------
// scanA: per-bucket exclusive scan of its PWG-length row; bucket total out.
// ---------------------------------------------------------------------------
__global__ __launch_bounds__(256) void scanA_kernel(int* __restrict__ hist,
                                                    int* __restrict__ bucketTot)
{
    __shared__ int s[256];
    const int b = blockIdx.x, tid = threadIdx.x;
    int v = hist[b * PWG + tid];
    s[tid] = v;
    __syncthreads();
#pragma unroll
    for (int o = 1; o < 256; o <<= 1) {
        int t = (tid >= o) ? s[tid - o] : 0;
        __syncthreads();
        s[tid] += t;
        __syncthreads();
    }
    hist[b * PWG + tid] = s[tid] - v;  // exclusive within bucket
    if (tid == 255) bucketTot[b] = s[255];
}

// ---------------------------------------------------------------------------
// part_gemm1: role-split fused kernel.
//  blocks [0,PWG): partition — computes bucketBase scan in LDS from bucketTot,
//    then scatters edges (packed 4B) into private per-bucket sub-regions.
//  blocks [PWG,..): GEMM1 (MFMA, 64x64 tile, BK=64, reg-pipelined)
//    h1b = bf16(x)@bf16(W1) with fused el1/er1 epilogue.
// ---------------------------------------------------------------------------
__global__ __launch_bounds__(256) void part_gemm1_kernel(
    const int* __restrict__ src, const int* __restrict__ dst,
    const int* __restrict__ hist, const int* __restrict__ bucketTot,
    unsigned* __restrict__ ebuf, int Ee, int chunk, int NB,
    const float* __restrict__ x, const ushort* __restrict__ W1t,
    const float* __restrict__ al1, const float* __restrict__ ar1,
    ushort* __restrict__ h1b, float* __restrict__ el1,
    float* __restrict__ er1, int Nn)
{
    __shared__ ushort As[64 * 72];
    __shared__ ushort Bs[64 * 72];

    if (blockIdx.x < PWG) {
        // ---------------- partition role (LDS aliased into As/Bs) ----------
        int* cur = (int*)As;     // NBMAX ints = 2 KB
        int* stmp = (int*)Bs;    // 256 ints
        const int wg = blockIdx.x, tid = threadIdx.x;
        int v = (tid < NB) ? bucketTot[tid] : 0;
        stmp[tid] = v;
        __syncthreads();
#pragma unroll
        for (int o = 1; o < 256; o <<= 1) {
            int t = (tid >= o) ? stmp[tid - o] : 0;
            __syncthreads();
            stmp[tid] += t;
            __syncthreads();
        }
        if (tid < NB) cur[tid] = hist[tid * PWG + wg] + (stmp[tid] - v);
        __syncthreads();
        const int beg = wg * chunk;
        const int endv = min(Ee, beg + chunk);
        for (int i = beg + tid; i < endv; i += 256) {
            int d = dst[i];
            int p = atomicAdd(&cur[d >> BSH], 1);
            ebuf[p] = ((unsigned)(d & ((1 << BSH) - 1)) << SRCB) | (unsigned)src[i];
        }
        return;
    }

    // ---------------- GEMM1 role -------------------------------------------
    const int t = threadIdx.x;
    const int lane = t & 63, w = t >> 6;
    const int tile = (blockIdx.x - PWG) * 64;

    f32x4 acc[4] = {};

    const int sr = t >> 2;          // 0..63 (row for A, col for B)
    const int sk = (t & 3) * 16;    // k offset 0,16,32,48
    const int arow = tile + sr;
    const bool rowok = arow < Nn;
    const float* xrow = x + (size_t)arow * 512;
    const ushort* wrow = W1t + (size_t)sr * 512;

    const int r = lane & 15, g = lane >> 4;

    // prologue: load tile k0=0 into regs
    float4 f0 = make_float4(0.f, 0.f, 0.f, 0.f), f1 = f0, f2 = f0, f3 = f0;
    bf16x8 bv0, bv1;
    if (rowok) {
        f0 = *(const float4*)(xrow + sk);
        f1 = *(const float4*)(xrow + sk + 4);
        f2 = *(const float4*)(xrow + sk + 8);
        f3 = *(const float4*)(xrow + sk + 12);
    }
    bv0 = *(const bf16x8*)(wrow + sk);
    bv1 = *(const bf16x8*)(wrow + sk + 8);

    for (int k0 = 0; k0 < 512; k0 += 64) {
        // stage regs -> LDS (A packed via v_perm, single b128 stores)
        uint4 aw0, aw1;
        aw0.x = pkbf(f0.x, f0.y); aw0.y = pkbf(f0.z, f0.w);
        aw0.z = pkbf(f1.x, f1.y); aw0.w = pkbf(f1.z, f1.w);
        aw1.x = pkbf(f2.x, f2.y); aw1.y = pkbf(f2.z, f2.w);
        aw1.z = pkbf(f3.x, f3.y); aw1.w = pkbf(f3.z, f3.w);
        *(uint4*)&As[sr * 72 + sk] = aw0;
        *(uint4*)&As[sr * 72 + sk + 8] = aw1;
        *(bf16x8*)&Bs[sr * 72 + sk] = bv0;
        *(bf16x8*)&Bs[sr * 72 + sk + 8] = bv1;
        __syncthreads();

        // issue next tile's global loads (overlap with MFMA below)
        int k1 = k0 + 64;
        if (k1 < 512) {
            if (rowok) {
                f0 = *(const float4*)(xrow + k1 + sk);
                f1 = *(const float4*)(xrow + k1 + sk + 4);
                f2 = *(const float4*)(xrow + k1 + sk + 8);
                f3 = *(const float4*)(xrow + k1 + sk + 12);
            }
            bv0 = *(const bf16x8*)(wrow + k1 + sk);
            bv1 = *(const bf16x8*)(wrow + k1 + sk + 8);
        }

        bf16x8 af0 = *(const bf16x8*)&As[(w * 16 + r) * 72 + g * 8];
        bf16x8 af1 = *(const bf16x8*)&As[(w * 16 + r) * 72 + 32 + g * 8];
#pragma unroll
        for (int cb = 0; cb < 4; cb++) {
            bf16x8 bf0 = *(const bf16x8*)&Bs[(cb * 16 + r) * 72 + g * 8];
            acc[cb] = __builtin_amdgcn_mfma_f32_16x16x32_bf16(af0, bf0, acc[cb], 0, 0, 0);
        }
#pragma unroll
        for (int cb = 0; cb < 4; cb++) {
            bf16x8 bf1 = *(const bf16x8*)&Bs[(cb * 16 + r) * 72 + 32 + g * 8];
            acc[cb] = __builtin_amdgcn_mfma_f32_16x16x32_bf16(af1, bf1, acc[cb], 0, 0, 0);
        }
        __syncthreads();
    }

    // epilogue: store h1b + fused el1/er1 from fp32 acc.
    float alv[4], arv[4];
#pragma unroll
    for (int cb = 0; cb < 4; cb++) {
        alv[cb] = al1[cb * 16 + r];
        arv[cb] = ar1[cb * 16 + r];
    }
#pragma unroll
    for (int v = 0; v < 4; v++) {
        int row = tile + w * 16 + g * 4 + v;
        bool ok = row < Nn;
#pragma unroll
        for (int cb = 0; cb < 4; cb++) {
            if (ok) h1b[(size_t)row * 64 + cb * 16 + r] = f2bf(acc[cb][v]);
            float pel = acc[cb][v] * alv[cb];
            float per = acc[cb][v] * arv[cb];
            pel += __shfl_xor(pel, 1); per += __shfl_xor(per, 1);
            pel += __shfl_xor(pel, 2); per += __shfl_xor(per, 2);
            pel += __shfl_xor(pel, 4); per += __shfl_xor(per, 4);
            if (ok && (r & 7) == 0) {
                int head = cb * 2 + (r >> 3);
                el1[row * 8 + head] = pel;
                er1[row * 8 + head] = per;
            }
        }
    }
}

// ---------------------------------------------------------------------------
// bucket_csr: derives its own [bb,be) from bucketTot scan; LDS-staged edges ->
// node histogram -> scan -> row_start + perm_src scatter in bucket window.
// ---------------------------------------------------------------------------
__global__ __launch_bounds__(512) void bucket_csr_kernel(const unsigned* __restrict__ ebuf,
                                                         const int* __restrict__ bucketTot,
                                                         int* __restrict__ row_start,
                                                         int* __restrict__ perm_src,
                                                         int Nn, int Ee, int NB)
{
    __shared__ unsigned stage[CSRCAP];
    __shared__ int cnt[512];
    __shared__ int s[512];
    __shared__ int cur[512];
    __shared__ int bt[256];
    const int b = blockIdx.x, tid = threadIdx.x;
    const int base = b << BSH;

    // inclusive scan of bucketTot (NB <= 256) to derive bb/be
    if (tid < 256) bt[tid] = (tid < NB) ? bucketTot[tid] : 0;
    __syncthreads();
#pragma unroll
    for (int o = 1; o < 256; o <<= 1) {
        int t = (tid >= o && tid < 256) ? bt[tid - o] : 0;
        __syncthreads();
        if (tid < 256) bt[tid] += t;
        __syncthreads();
    }
    const int be = bt[b];
    const int bb = be - bucketTot[b];
    const int m = be - bb;

    cnt[tid] = 0;
    __syncthreads();
    for (int idx = tid; idx < m; idx += 512) {
        unsigned pk = ebuf[bb + idx];
        if (idx < CSRCAP) stage[idx] = pk;
        atomicAdd(&cnt[pk >> SRCB], 1);
    }
    __syncthreads();
    int v = cnt[tid];
    s[tid] = v;
    __syncthreads();
#pragma unroll
    for (int o = 1; o < 512; o <<= 1) {
        int t = (tid >= o) ? s[tid - o] : 0;
        __syncthreads();
        s[tid] += t;
        __syncthreads();
    }
    const int off = bb + s[tid] - v;
    const int node = base + tid;
    if (node < Nn) row_start[node] = off;
    cur[tid] = off;
    __syncthreads();
    for (int idx = tid; idx < m; idx += 512) {
        unsigned pk = (idx < CSRCAP) ? stage[idx] : ebuf[bb + idx];
        int p = atomicAdd(&cur[pk >> SRCB], 1);
        perm_src[p] = (int)(pk & ((1u << SRCB) - 1u));
    }
    if (b == NB - 1 && tid == 0) row_start[Nn] = Ee;
}

// ---------------------------------------------------------------------------
// agg1: one wave per dst node, 16 edges in flight per iteration.
// Lane group g = lane>>4 serves edges j+g, j+4+g, j+8+g, j+12+g; lane
// q = lane&15 loads features 4q..4q+3 as ushort4 (8B). Head h = q>>1.
// ---------------------------------------------------------------------------
__global__ __launch_bounds__(256) void agg1_kernel(
    const ushort* __restrict__ h1b, const float* __restrict__ el1,
    const float* __restrict__ er1, const int* __restrict__ row_start,
    const int* __restrict__ perm_src, const float* __restrict__ b1,
    ushort* __restrict__ hmidb, int Nn)
{
    const int wid = (blockIdx.x * blockDim.x + threadIdx.x) >> 6;
    const int lane = threadIdx.x & 63;
    if (wid >= Nn) return;
    const int g = lane >> 4;      // edge sub-group 0..3
    const int q = lane & 15;      // feature quad
    const int h = q >> 1;         // head
    const int beg = row_start[wid], end = row_start[wid + 1];
    const float er = er1[wid * 8 + h];

    float a0 = 0.f, a1 = 0.f, a2 = 0.f, a3 = 0.f, denom = 0.f;
    for (int i0 = beg; i0 < end; i0 += 64) {
        const int cnt = min(end - i0, 64);
        int pv = (i0 + lane < end) ? perm_src[i0 + lane] : 0;
        for (int j = 0; j < cnt; j += 16) {
            const int e0 = j + g, e1 = j + 4 + g, e2 = j + 8 + g, e3 = j + 12 + g;
            const int s0 = __shfl(pv, min(e0, cnt - 1));
            const int s1 = __shfl(pv, min(e1, cnt - 1));
            const int s2 = __shfl(pv, min(e2, cnt - 1));
            const int s3 = __shfl(pv, min(e3, cnt - 1));
            ushort4 r0 = *(const ushort4*)&h1b[(size_t)s0 * 64 + q * 4];
            ushort4 r1 = *(const ushort4*)&h1b[(size_t)s1 * 64 + q * 4];
            ushort4 r2 = *(const ushort4*)&h1b[(size_t)s2 * 64 + q * 4];
            ushort4 r3 = *(const ushort4*)&h1b[(size_t)s3 * 64 + q * 4];
            float x0 = el1[s0 * 8 + h];
            float x1 = el1[s1 * 8 + h];
            float x2 = el1[s2 * 8 + h];
            float x3 = el1[s3 * 8 + h];
            float e;
            e = x0 + er; e = (e >= 0.f) ? e : 0.2f * e;
            float w0 = (e0 < cnt) ? __expf(e) : 0.f;
            e = x1 + er; e = (e >= 0.f) ? e : 0.2f * e;
            float w1 = (e1 < cnt) ? __expf(e) : 0.f;
            e = x2 + er; e = (e >= 0.f) ? e : 0.2f * e;
            float w2 = (e2 < cnt) ? __expf(e) : 0.f;
            e = x3 + er; e = (e >= 0.f) ? e : 0.2f * e;
            float w3 = (e3 < cnt) ? __expf(e) : 0.f;
            denom += (w0 + w1) + (w2 + w3);
            a0 += bf2f(r0.x) * w0 + bf2f(r1.x) * w1 + bf2f(r2.x) * w2 + bf2f(r3.x) * w3;
            a1 += bf2f(r0.y) * w0 + bf2f(r1.y) * w1 + bf2f(r2.y) * w2 + bf2f(r3.y) * w3;
            a2 += bf2f(r0.z) * w0 + bf2f(r1.z) * w1 + bf2f(r2.z) * w2 + bf2f(r3.z) * w3;
            a3 += bf2f(r0.w) * w0 + bf2f(r1.w) * w1 + bf2f(r2.w) * w2 + bf2f(r3.w) * w3;
        }
    }
    // merge the 4 edge groups
    denom += __shfl_xor(denom, 16); denom += __shfl_xor(denom, 32);
    a0 += __shfl_xor(a0, 16); a0 += __shfl_xor(a0, 32);
    a1 += __shfl_xor(a1, 16); a1 += __shfl_xor(a1, 32);
    a2 += __shfl_xor(a2, 16); a2 += __shfl_xor(a2, 32);
    a3 += __shfl_xor(a3, 16); a3 += __shfl_xor(a3, 32);
    if (g == 0) {
        const float4 bv = *(const float4*)&b1[q * 4];
        const float inv = 1.f / (denom + 1e-9f);
        float v0 = a0 * inv + bv.x;
        float v1 = a1 * inv + bv.y;
        float v2 = a2 * inv + bv.z;
        float v3 = a3 * inv + bv.w;
        v0 = (v0 > 0.f) ? v0 : expm1f(v0);
        v1 = (v1 > 0.f) ? v1 : expm1f(v1);
        v2 = (v2 > 0.f) ? v2 : expm1f(v2);
        v3 = (v3 > 0.f) ? v3 : expm1f(v3);
        uint2 o;
        o.x = pkbf(v0, v1);
        o.y = pkbf(v2, v3);
        *(uint2*)&hmidb[(size_t)wid * 64 + q * 4] = o;
    }
}

// ---------------------------------------------------------------------------
// GEMM2: h2b = hmid @ W2 (bf16 in, bf16 out, padded rows w/ embedded el2/er2).
// One thread per node (lane-parallel over nodes; W2 broadcast from LDS).
// ---------------------------------------------------------------------------
__global__ __launch_bounds__(256) void gemm2_kernel(
    const ushort* __restrict__ hmidb, const float* __restrict__ W2,
    const float* __restrict__ wal2, const float* __restrict__ war2,
    ushort* __restrict__ h2b, int Nn)
{
    __shared__ float w2s[64 * NCLS];
    __shared__ float wals[64], wars[64];
    for (int i = threadIdx.x; i < 64 * NCLS; i += blockDim.x) w2s[i] = W2[i];
    if (threadIdx.x < 64) {
        wals[threadIdx.x] = wal2[threadIdx.x];
        wars[threadIdx.x] = war2[threadIdx.x];
    }
    __syncthreads();
    int n = blockIdx.x * blockDim.x + threadIdx.x;
    if (n >= Nn) return;

    float out[NCLS];
#pragma unroll
    for (int c = 0; c < NCLS; c++) out[c] = 0.f;
    float accel = 0.f, accer = 0.f;

#pragma unroll 4
    for (int k4 = 0; k4 < 16; k4++) {
        ushort4 u = *(const ushort4*)&hmidb[(size_t)n * 64 + k4 * 4];
        float h0 = bf2f(u.x), h1 = bf2f(u.y), h2 = bf2f(u.z), h3 = bf2f(u.w);
        accel += h0 * wals[k4 * 4] + h1 * wals[k4 * 4 + 1] + h2 * wals[k4 * 4 + 2] + h3 * wals[k4 * 4 + 3];
        accer += h0 * wars[k4 * 4] + h1 * wars[k4 * 4 + 1] + h2 * wars[k4 * 4 + 2] + h3 * wars[k4 * 4 + 3];
#pragma unroll
        for (int c = 0; c < NCLS; c++) {
            out[c] += h0 * w2s[(k4 * 4 + 0) * NCLS + c] + h1 * w2s[(k4 * 4 + 1) * NCLS + c] +
                      h2 * w2s[(k4 * 4 + 2) * NCLS + c] + h3 * w2s[(k4 * 4 + 3) * NCLS + c];
        }
    }
    ushort* row = h2b + (size_t)n * H2S;
#pragma unroll
    for (int c = 0; c < NCLS; c += 2) {
        *(unsigned*)&row[c] = pkbf(out[c], out[c + 1]);
    }
    ((float*)row)[20] = accel;  // el2
    ((float*)row)[21] = accer;  // er2
}

// ---------------------------------------------------------------------------
// agg2 + log_softmax: one wave per dst node, 16 edges in flight/iteration.
// Group g serves edges j+g, j+4+g, j+8+g, j+12+g; lanes q<10 load the 80B
// class row as ushort4; el2 read from the same 128B line (embedded).
// ---------------------------------------------------------------------------
__global__ __launch_bounds__(256) void agg2_kernel(
    const ushort* __restrict__ h2b, const int* __restrict__ row_start,
    const int* __restrict__ perm_src, const float* __restrict__ b2,
    float* __restrict__ out, int Nn)
{
    const int wid = (blockIdx.x * blockDim.x + threadIdx.x) >> 6;
    const int lane = threadIdx.x & 63;
    if (wid >= Nn) return;
    const int g = lane >> 4;
    const int q = lane & 15;
    const int beg = row_start[wid], end = row_start[wid + 1];
    const float er = ((const float*)(h2b + (size_t)wid * H2S))[21];

    float a0 = 0.f, a1 = 0.f, a2 = 0.f, a3 = 0.f, denom = 0.f;
    for (int i0 = beg; i0 < end; i0 += 64) {
        const int cnt = min(end - i0, 64);
        int pv = (i0 + lane < end) ? perm_src[i0 + lane] : 0;
        for (int j = 0; j < cnt; j += 16) {
            const int e0 = j + g, e1 = j + 4 + g, e2 = j + 8 + g, e3 = j + 12 + g;
            const int s0 = __shfl(pv, min(e0, cnt - 1));
            const int s1 = __shfl(pv, min(e1, cnt - 1));
            const int s2 = __shfl(pv, min(e2, cnt - 1));
            const int s3 = __shfl(pv, min(e3, cnt - 1));
            const ushort* rp0 = h2b + (size_t)s0 * H2S;
            const ushort* rp1 = h2b + (size_t)s1 * H2S;
            const ushort* rp2 = h2b + (size_t)s2 * H2S;
            const ushort* rp3 = h2b + (size_t)s3 * H2S;
            ushort4 r0 = *(const ushort4*)(rp0 + q * 4);
            ushort4 r1 = *(const ushort4*)(rp1 + q * 4);
            ushort4 r2 = *(const ushort4*)(rp2 + q * 4);
            ushort4 r3 = *(const ushort4*)(rp3 + q * 4);
            float x0 = ((const float*)rp0)[20];
            float x1 = ((const float*)rp1)[20];
            float x2 = ((const float*)rp2)[20];
            float x3 = ((const float*)rp3)[20];
            float e;
            e = x0 + er; e = (e >= 0.f) ? e : 0.2f * e;
            float w0 = (e0 < cnt) ? __expf(e) : 0.f;
            e = x1 + er; e = (e >= 0.f) ? e : 0.2f * e;
            float w1 = (e1 < cnt) ? __expf(e) : 0.f;
            e = x2 + er; e = (e >= 0.f) ? e : 0.2f * e;
            float w2 = (e2 < cnt) ? __expf(e) : 0.f;
            e = x3 + er; e = (e >= 0.f) ? e : 0.2f * e;
            float w3 = (e3 < cnt) ? __expf(e) : 0.f;
            denom += (w0 + w1) + (w2 + w3);
            a0 += bf2f(r0.x) * w0 + bf2f(r1.x) * w1 + bf2f(r2.x) * w2 + bf2f(r3.x) * w3;
            a1 += bf2f(r0.y) * w0 + bf2f(r1.y) * w1 + bf2f(r2.y) * w2 + bf2f(r3.y) * w3;
            a2 += bf2f(r0.z) * w0 + bf2f(r1.z) * w1 + bf2f(r2.z) * w2 + bf2f(r3.z) * w3;
            a3 += bf2f(r0.w) * w0 + bf2f(r1.w) * w1 + bf2f(r2.w) * w2 + bf2f(r3.w) * w3;
        }
    }
    // merge the 4 edge groups
    denom += __shfl_xor(denom, 16); denom += __shfl_xor(denom, 32);
    a0 += __shfl_xor(a0, 16); a0 += __shfl_xor(a0, 32);
    a1 += __shfl_xor(a1, 16); a1 += __shfl_xor(a1, 32);
    a2 += __shfl_xor(a2, 16); a2 += __shfl_xor(a2, 32);
    a3 += __shfl_xor(a3, 16); a3 += __shfl_xor(a3, 32);

    const bool act = (g == 0) && (q < 10);
    float v0, v1, v2, v3;
    if (act) {
        const float4 bv = *(const float4*)&b2[q * 4];
        const float inv = 1.f / (denom + 1e-9f);
        v0 = a0 * inv + bv.x;
        v1 = a1 * inv + bv.y;
        v2 = a2 * inv + bv.z;
        v3 = a3 * inv + bv.w;
    } else {
        v0 = v1 = v2 = v3 = -1e30f;
    }
    // log_softmax over 40 classes (10 lanes x 4)
    float mx = fmaxf(fmaxf(v0, v1), fmaxf(v2, v3));
#pragma unroll
    for (int o = 1; o < 64; o <<= 1) mx = fmaxf(mx, __shfl_xor(mx, o));
    float sx = act ? (__expf(v0 - mx) + __expf(v1 - mx) + __expf(v2 - mx) + __expf(v3 - mx)) : 0.f;
#pragma unroll
    for (int o = 1; o < 64; o <<= 1) sx += __shfl_xor(sx, o);
    if (act) {
        float lg = mx + __logf(sx);
        float4 o4 = make_float4(v0 - lg, v1 - lg, v2 - lg, v3 - lg);
        *(float4*)&out[(size_t)wid * NCLS + q * 4] = o4;
    }
}

// ---------------------------------------------------------------------------
extern "C" void kernel_launch(void* const* d_in, const int* in_sizes, int n_in,
                              void* d_out, int out_size, void* d_ws, size_t ws_size,
                              hipStream_t stream)
{
    const float* x   = (const float*)d_in[0];
    const int*   src = (const int*)d_in[1];
    const int*   dst = (const int*)d_in[2];
    const float* W1  = (const float*)d_in[3];
    const float* al1 = (const float*)d_in[4];
    const float* ar1 = (const float*)d_in[5];
    const float* b1  = (const float*)d_in[6];
    const float* W2  = (const float*)d_in[7];
    const float* al2 = (const float*)d_in[8];
    const float* ar2 = (const float*)d_in[9];
    const float* b2  = (const float*)d_in[10];
    float* out = (float*)d_out;

    const int Nn = in_sizes[0] / 512;
    const int Ee = in_sizes[1];
    const int NB = (Nn + (1 << BSH) - 1) >> BSH;   // buckets of 512 nodes (<=256)
    const int chunk = (Ee + PWG - 1) / PWG;

    // workspace layout (16B-aligned bump allocator)
    char* wsb = (char*)d_ws;
    size_t off = 0;
    auto alloc = [&](size_t bytes) -> void* {
        off = (off + 15) & ~(size_t)15;
        void* p = wsb + off;
        off += bytes;
        return p;
    };
    ushort* h1b   = (ushort*)alloc((size_t)Nn * 64 * 2);
    ushort* hmidb = (ushort*)alloc((size_t)Nn * 64 * 2);
    ushort* h2b   = (ushort*)alloc((size_t)Nn * H2S * 2);
    ushort* W1t   = (ushort*)alloc(64 * 512 * 2);
    float* el1  = (float*)alloc((size_t)Nn * 8 * 4);
    float* er1  = (float*)alloc((size_t)Nn * 8 * 4);
    float* wal2 = (float*)alloc(64 * 4);
    float* war2 = (float*)alloc(64 * 4);
    int* row_start  = (int*)alloc((size_t)(Nn + 1) * 4);
    int* hist       = (int*)alloc((size_t)NB * PWG * 4);
    int* bucketTot  = (int*)alloc((size_t)NB * 4);
    int* perm_src   = (int*)alloc((size_t)Ee * 4);
    unsigned* ebuf  = (unsigned*)alloc((size_t)Ee * 4);

    // CSR build + weight prep; partition overlapped with gemm1 (role-split)
    hist_prep_kernel<<<PWG + 129, 256, 0, stream>>>(dst, hist, Ee, chunk, NB,
                                                    W1, W1t, W2, al2, ar2, wal2, war2);
    scanA_kernel<<<NB, 256, 0, stream>>>(hist, bucketTot);
    part_gemm1_kernel<<<PWG + (Nn + 63) / 64, 256, 0, stream>>>(
        src, dst, hist, bucketTot, ebuf, Ee, chunk, NB,
        x, W1t, al1, ar1, h1b, el1, er1, Nn);
    bucket_csr_kernel<<<NB, 512, 0, stream>>>(ebuf, bucketTot, row_start, perm_src, Nn, Ee, NB);

    // layer 1 aggregation
    agg1_kernel<<<(Nn + 3) / 4, 256, 0, stream>>>(h1b, el1, er1, row_start, perm_src, b1, hmidb, Nn);

    // layer 2
    gemm2_kernel<<<(Nn + 255) / 256, 256, 0, stream>>>(hmidb, W2, wal2, war2, h2b, Nn);
    agg2_kernel<<<(Nn + 3) / 4, 256, 0, stream>>>(h2b, row_start, perm_src, b2, out, Nn);
}